// Round 1
// baseline (1098.137 us; speedup 1.0000x reference)
//
#include <hip/hip_runtime.h>

// Problem constants
#define BB     64
#define HH     2048
#define NHH    16
#define NKVV   2
#define NREPP  8
#define HDD    128
#define MAXLENN 8192
#define QKVN   2560   // 2048 + 256 + 256
#define CHUNKS 16
#define CHUNK_SZ 512  // MAXLEN / CHUNKS

// ---------------------------------------------------------------------------
// Generic split-K GEMM: out[b][n] = sum_k A[b][k] * W[n][k]
// A: [64][2048] row-major. W segmented (wq/wk/wv) or single (wo).
// Partials: outPart[s][64][Ntot], s = split index (8 splits of 256 over K=2048)
// Tile: M=64 (all), N=64, BK=32. Block 256 threads.
// ---------------------------------------------------------------------------
__global__ __launch_bounds__(256) void gemm_splitk(
    const float* __restrict__ A,
    const float* __restrict__ W0, const float* __restrict__ W1,
    const float* __restrict__ W2,
    int seg1, int seg2,
    float* __restrict__ outPart, int Ntot)
{
    const int n0  = blockIdx.x * 64;
    const int s   = blockIdx.y;
    const int tid = threadIdx.x;

    const float* W = W0; int wrow = n0;
    if (n0 >= seg2)      { W = W2; wrow = n0 - seg2; }
    else if (n0 >= seg1) { W = W1; wrow = n0 - seg1; }

    __shared__ float At[32][68];   // [k][row], padded
    __shared__ float Wt[32][68];

    float acc[4][4];
#pragma unroll
    for (int i = 0; i < 4; ++i)
#pragma unroll
        for (int j = 0; j < 4; ++j) acc[i][j] = 0.f;

    const int r  = tid >> 3;           // 0..31
    const int c  = (tid & 7) << 2;     // 0,4,..,28
    const int ty = tid >> 4;           // 0..15 -> rows 4ty..
    const int tx = tid & 15;           // 0..15 -> cols 4tx..

    for (int kt = 0; kt < 8; ++kt) {
        const int k0 = s * 256 + kt * 32;
        float4 a0 = *(const float4*)&A[(size_t)r        * 2048 + k0 + c];
        float4 a1 = *(const float4*)&A[(size_t)(r + 32) * 2048 + k0 + c];
        float4 w0 = *(const float4*)&W[(size_t)(wrow + r)      * 2048 + k0 + c];
        float4 w1 = *(const float4*)&W[(size_t)(wrow + r + 32) * 2048 + k0 + c];
        __syncthreads();
        At[c + 0][r] = a0.x; At[c + 1][r] = a0.y; At[c + 2][r] = a0.z; At[c + 3][r] = a0.w;
        At[c + 0][r + 32] = a1.x; At[c + 1][r + 32] = a1.y; At[c + 2][r + 32] = a1.z; At[c + 3][r + 32] = a1.w;
        Wt[c + 0][r] = w0.x; Wt[c + 1][r] = w0.y; Wt[c + 2][r] = w0.z; Wt[c + 3][r] = w0.w;
        Wt[c + 0][r + 32] = w1.x; Wt[c + 1][r + 32] = w1.y; Wt[c + 2][r + 32] = w1.z; Wt[c + 3][r + 32] = w1.w;
        __syncthreads();
#pragma unroll
        for (int kk = 0; kk < 32; ++kk) {
            float4 av = *(const float4*)&At[kk][ty * 4];
            float4 wv = *(const float4*)&Wt[kk][tx * 4];
            acc[0][0] += av.x * wv.x; acc[0][1] += av.x * wv.y; acc[0][2] += av.x * wv.z; acc[0][3] += av.x * wv.w;
            acc[1][0] += av.y * wv.x; acc[1][1] += av.y * wv.y; acc[1][2] += av.y * wv.z; acc[1][3] += av.y * wv.w;
            acc[2][0] += av.z * wv.x; acc[2][1] += av.z * wv.y; acc[2][2] += av.z * wv.z; acc[2][3] += av.z * wv.w;
            acc[3][0] += av.w * wv.x; acc[3][1] += av.w * wv.y; acc[3][2] += av.w * wv.z; acc[3][3] += av.w * wv.w;
        }
    }
#pragma unroll
    for (int i = 0; i < 4; ++i) {
        float4 o = { acc[i][0], acc[i][1], acc[i][2], acc[i][3] };
        *(float4*)&outPart[(size_t)(s * 64 + ty * 4 + i) * Ntot + n0 + tx * 4] = o;
    }
}

// ---------------------------------------------------------------------------
// Combine QKV split-K partials + bias, apply RoPE, write q_rot + KV cache
// Grid: 64 (batch), 256 threads
// ---------------------------------------------------------------------------
__global__ __launch_bounds__(256) void rope_cache_kernel(
    const float* __restrict__ qkv_part,   // [8][64][2560]
    const float* __restrict__ bq, const float* __restrict__ bk,
    const float* __restrict__ bv,
    const float* __restrict__ cosp, const float* __restrict__ sinp,
    float* __restrict__ q_rot,            // [64][16][128]
    float* __restrict__ cache_k, float* __restrict__ cache_v,
    const int* __restrict__ start_pos)
{
    const int b = blockIdx.x, tid = threadIdx.x;
    __shared__ float comb[QKVN];

    for (int j = tid; j < QKVN; j += 256) {
        float v = 0.f;
#pragma unroll
        for (int s = 0; s < 8; ++s) v += qkv_part[(size_t)(s * 64 + b) * QKVN + j];
        float bias = (j < 2048) ? bq[j] : (j < 2304 ? bk[j - 2048] : bv[j - 2304]);
        comb[j] = v + bias;
    }
    __syncthreads();

    const int sp = *start_pos;
    for (int idx = tid; idx < 1280; idx += 256) {
        const int hh = idx >> 6, dp = idx & 63;
        const float cs_lo = cosp[dp], sn_lo = sinp[dp];
        const float cs_hi = cosp[dp + 64], sn_hi = sinp[dp + 64];
        if (hh < 16) {
            float a  = comb[hh * 128 + dp];
            float b2 = comb[hh * 128 + 64 + dp];
            q_rot[(size_t)(b * 16 + hh) * 128 + dp]      = a * cs_lo - b2 * sn_lo;
            q_rot[(size_t)(b * 16 + hh) * 128 + 64 + dp] = b2 * cs_hi + a * sn_hi;
        } else if (hh < 18) {
            const int g = hh - 16;
            float a  = comb[2048 + g * 128 + dp];
            float b2 = comb[2048 + g * 128 + 64 + dp];
            float* dst = cache_k + (((size_t)b * MAXLENN + sp) * NKVV + g) * HDD;
            dst[dp]      = a * cs_lo - b2 * sn_lo;
            dst[64 + dp] = b2 * cs_hi + a * sn_hi;
        } else {
            const int g = hh - 18;
            float a  = comb[2304 + g * 128 + dp];
            float b2 = comb[2304 + g * 128 + 64 + dp];
            float* dst = cache_v + (((size_t)b * MAXLENN + sp) * NKVV + g) * HDD;
            dst[dp]      = a;
            dst[64 + dp] = b2;
        }
    }
}

// ---------------------------------------------------------------------------
// Flash-decode attention pass 1.
// Grid: (chunk=16, g=2, b=64), 256 threads = 4 waves.
// Wave w handles positions [chunk*512 + w*128, +128) for ALL 8 reps.
// Writes one partial (m, l, o[128]) per (b, head, chunk).
// ---------------------------------------------------------------------------
__global__ __launch_bounds__(256) void attn_kernel(
    const float* __restrict__ q_rot,
    const float* __restrict__ cache_k, const float* __restrict__ cache_v,
    const int* __restrict__ start_pos,
    float* __restrict__ attn_part)        // [64][16][16][132]
{
    const int chunk = blockIdx.x;
    const int g     = blockIdx.y;
    const int b     = blockIdx.z;
    const int tid   = threadIdx.x;
    const int w     = tid >> 6;
    const int lane  = tid & 63;

    __shared__ float smem[5120];          // 20 KB
    float* q_s  = smem;                   // [8][128]
    float* p_s  = smem + 1024;            // [4][8][128]
    float* o_s  = smem;                   // alias (after sync): [4][8][128]
    float* ml_s = smem + 4096;            // alias: [4][8][2]

    // stage q for this (b, g): 8 reps x 128 dims
    {
        const int r = tid >> 5, d4 = (tid & 31) << 2;
        *(float4*)&q_s[r * 128 + d4] =
            *(const float4*)&q_rot[(size_t)((b * 16 + g * 8 + r)) * 128 + d4];
    }
    __syncthreads();

    const int end_pos = *start_pos + 1;
    const int base = chunk * CHUNK_SZ + w * 128;
    const int posA = base + lane, posB = posA + 64;
    const float scale = 0.08838834764831845f; // 1/sqrt(128)

    // ---- Phase A: dots for 2 positions/lane, 8 reps ----
    float dotsA[8], dotsB[8];
#pragma unroll
    for (int r = 0; r < 8; ++r) { dotsA[r] = 0.f; dotsB[r] = 0.f; }

    const float4* kA = (const float4*)(cache_k + (((size_t)b * MAXLENN + posA) * NKVV + g) * HDD);
    const float4* kB = (const float4*)(cache_k + (((size_t)b * MAXLENN + posB) * NKVV + g) * HDD);
#pragma unroll 4
    for (int dc = 0; dc < 32; ++dc) {
        float4 ka = kA[dc], kb = kB[dc];
#pragma unroll
        for (int r = 0; r < 8; ++r) {
            float4 q4 = *(const float4*)&q_s[r * 128 + dc * 4]; // wave-uniform broadcast
            dotsA[r] += ka.x * q4.x + ka.y * q4.y + ka.z * q4.z + ka.w * q4.w;
            dotsB[r] += kb.x * q4.x + kb.y * q4.y + kb.z * q4.z + kb.w * q4.w;
        }
    }

    const bool vA = (posA < end_pos), vB = (posB < end_pos);
    float m[8], lsum[8];
#pragma unroll
    for (int r = 0; r < 8; ++r) {
        float da = vA ? dotsA[r] * scale : -3e30f;
        float db = vB ? dotsB[r] * scale : -3e30f;
        float mx = fmaxf(da, db);
#pragma unroll
        for (int off = 32; off >= 1; off >>= 1) mx = fmaxf(mx, __shfl_xor(mx, off));
        float pa, pb;
        if (mx < -1e29f) { pa = 0.f; pb = 0.f; }
        else { pa = __expf(da - mx); pb = __expf(db - mx); }
        m[r] = mx;
        lsum[r] = pa + pb;
        p_s[(w * 8 + r) * 128 + lane]      = pa;
        p_s[(w * 8 + r) * 128 + 64 + lane] = pb;
    }

    // ---- Phase B: o[dim] = sum_pos p * v ; lane owns dims (2lane, 2lane+1) ----
    float2 o[8];
#pragma unroll
    for (int r = 0; r < 8; ++r) { o[r].x = 0.f; o[r].y = 0.f; }

    const float* vbase = cache_v + (((size_t)b * MAXLENN + base) * NKVV + g) * HDD + 2 * lane;
#pragma unroll 2
    for (int pg = 0; pg < 32; ++pg) {
        const float* vr = vbase + (size_t)pg * 1024;  // 4 positions * 256 floats
        float2 v0 = *(const float2*)(vr);
        float2 v1 = *(const float2*)(vr + 256);
        float2 v2 = *(const float2*)(vr + 512);
        float2 v3 = *(const float2*)(vr + 768);
#pragma unroll
        for (int r = 0; r < 8; ++r) {
            float4 p4 = *(const float4*)&p_s[(w * 8 + r) * 128 + pg * 4]; // broadcast
            o[r].x += p4.x * v0.x + p4.y * v1.x + p4.z * v2.x + p4.w * v3.x;
            o[r].y += p4.x * v0.y + p4.y * v1.y + p4.z * v2.y + p4.w * v3.y;
        }
    }

    // reduce l across lanes
#pragma unroll
    for (int r = 0; r < 8; ++r) {
        float l = lsum[r];
#pragma unroll
        for (int off = 32; off >= 1; off >>= 1) l += __shfl_xor(l, off);
        lsum[r] = l;
    }

    __syncthreads();   // all waves done reading q_s / p_s

    // publish per-wave partials
#pragma unroll
    for (int r = 0; r < 8; ++r)
        *(float2*)&o_s[(w * 8 + r) * 128 + 2 * lane] = o[r];
    if (lane == 0) {
#pragma unroll
        for (int r = 0; r < 8; ++r) {
            ml_s[(w * 8 + r) * 2]     = m[r];
            ml_s[(w * 8 + r) * 2 + 1] = lsum[r];
        }
    }
    __syncthreads();

    // block combine: thread -> (rep r2, dim group dd*4)
    const int r2 = tid >> 5, dd = tid & 31;
    float M = -3e30f;
#pragma unroll
    for (int ww = 0; ww < 4; ++ww) M = fmaxf(M, ml_s[(ww * 8 + r2) * 2]);
    float L = 0.f;
    float4 O; O.x = O.y = O.z = O.w = 0.f;
#pragma unroll
    for (int ww = 0; ww < 4; ++ww) {
        float sc = __expf(ml_s[(ww * 8 + r2) * 2] - M);
        L += sc * ml_s[(ww * 8 + r2) * 2 + 1];
        float4 ov = *(const float4*)&o_s[(ww * 8 + r2) * 128 + dd * 4];
        O.x += sc * ov.x; O.y += sc * ov.y; O.z += sc * ov.z; O.w += sc * ov.w;
    }
    float* outp = attn_part + ((size_t)(b * 16 + g * 8 + r2) * CHUNKS + chunk) * 132;
    if (dd == 0) { outp[0] = M; outp[1] = L; }
    *(float4*)&outp[4 + dd * 4] = O;
}

// ---------------------------------------------------------------------------
// Combine chunk partials -> attn_out [64][16*128]
// Grid: 1024 (b*16+h), 64 threads (lane owns dims 2lane, 2lane+1)
// ---------------------------------------------------------------------------
__global__ __launch_bounds__(64) void attn_combine(
    const float* __restrict__ attn_part, float* __restrict__ attn_out)
{
    const int bh = blockIdx.x;
    const int lane = threadIdx.x;
    const float* pp = attn_part + (size_t)bh * CHUNKS * 132;

    float M = -3e30f;
#pragma unroll
    for (int c = 0; c < CHUNKS; ++c) M = fmaxf(M, pp[c * 132]);
    float L = 0.f;
    float2 O = { 0.f, 0.f };
#pragma unroll
    for (int c = 0; c < CHUNKS; ++c) {
        float sc = __expf(pp[c * 132] - M);
        L += sc * pp[c * 132 + 1];
        O.x += sc * pp[c * 132 + 4 + 2 * lane];
        O.y += sc * pp[c * 132 + 4 + 2 * lane + 1];
    }
    const float inv = (L > 0.f) ? 1.0f / L : 0.f;
    float2 res = { O.x * inv, O.y * inv };
    *(float2*)&attn_out[(size_t)bh * 128 + 2 * lane] = res;
}

// ---------------------------------------------------------------------------
// Sum WO split-K partials into final output
// ---------------------------------------------------------------------------
__global__ __launch_bounds__(256) void wo_combine(
    const float* __restrict__ wo_part, float* __restrict__ out)
{
    const int i4 = blockIdx.x * 256 + threadIdx.x;   // float4 index, 32768 total
    float4 acc; acc.x = acc.y = acc.z = acc.w = 0.f;
#pragma unroll
    for (int s = 0; s < 8; ++s) {
        float4 v = *(const float4*)&wo_part[(size_t)s * (64 * 2048) + (size_t)i4 * 4];
        acc.x += v.x; acc.y += v.y; acc.z += v.z; acc.w += v.w;
    }
    *(float4*)&out[(size_t)i4 * 4] = acc;
}

// ---------------------------------------------------------------------------
extern "C" void kernel_launch(void* const* d_in, const int* in_sizes, int n_in,
                              void* d_out, int out_size, void* d_ws, size_t ws_size,
                              hipStream_t stream)
{
    const float* x      = (const float*)d_in[0];
    const float* cosp   = (const float*)d_in[1];
    const float* sinp   = (const float*)d_in[2];
    const float* wq     = (const float*)d_in[3];
    const float* bq     = (const float*)d_in[4];
    const float* wk     = (const float*)d_in[5];
    const float* bk     = (const float*)d_in[6];
    const float* wv     = (const float*)d_in[7];
    const float* bv     = (const float*)d_in[8];
    const float* wo     = (const float*)d_in[9];
    float* cache_k      = (float*)d_in[10];
    float* cache_v      = (float*)d_in[11];
    const int* start_pos = (const int*)d_in[12];
    float* out = (float*)d_out;

    // Workspace layout (floats), lifetime-overlapped:
    //  regionA (2,162,688 fl): qkv_part [8][64][2560] -> attn_part [64][16][16][132] -> wo_part [8][64][2048]
    //  q_rot    at 2,162,688 (131,072 fl)
    //  attn_out at 2,293,760 (131,072 fl)
    float* ws        = (float*)d_ws;
    float* qkv_part  = ws;
    float* attn_part = ws;
    float* wo_part   = ws;
    float* q_rot     = ws + 2162688;
    float* attn_out  = ws + 2162688 + 131072;

    gemm_splitk<<<dim3(40, 8), 256, 0, stream>>>(x, wq, wk, wv, 2048, 2304, qkv_part, QKVN);
    rope_cache_kernel<<<64, 256, 0, stream>>>(qkv_part, bq, bk, bv, cosp, sinp,
                                              q_rot, cache_k, cache_v, start_pos);
    attn_kernel<<<dim3(CHUNKS, NKVV, BB), 256, 0, stream>>>(q_rot, cache_k, cache_v,
                                                            start_pos, attn_part);
    attn_combine<<<BB * NHH, 64, 0, stream>>>(attn_part, attn_out);
    gemm_splitk<<<dim3(32, 8), 256, 0, stream>>>(attn_out, wo, wo, wo, 1 << 30, 1 << 30,
                                                 wo_part, 2048);
    wo_combine<<<128, 256, 0, stream>>>(wo_part, out);
}